// Round 2
// baseline (114.017 us; speedup 1.0000x reference)
//
#include <hip/hip_runtime.h>
#include <math.h>

// StripePolynomial2d: out[b,c,px,py] = sum_i lut_i(xs_i), where
//   xs_i = 0.5*x + Ax[i]*px + Ay[i]*py + C0[i]   (folded position map)
//   s = clamp(floor(xs),0,511); t = 2*(xs-s)-1; P = c0 + t*(c1 + t*c2)
// 1/8 normalization folded into staged coeffs; positions 0,1 merged
// (theta=0 => identical maps => sum their weights) -> 7 tables.
//
// R5b: row-contiguous lane mapping. Each wave covers 4 px rows x 64
// contiguous py (px = wv*4 + lane>>4, py = (lane&15)*4), so every
// global_load/store_dwordx4 covers 4x 256B fully-used runs (full 128B
// cache lines) instead of 16 half-lines. Gather bank spread per wave is
// 3*|Ax| + 60*|Ay| in [3,46] -> <=2 addrs/bank (2-way is free), theta=0
// table degenerates to 4 broadcast addrs. Output stores are nontemporal
// via native clang vector type (HIP float4 is a class the builtin rejects).
//
// R4: 128x64 tile (4 k-iters/thread) + software prefetch of x[k+1] to break
// the per-k load convoy; staging amortized over 2x more pixels.

#define WDIM 512
#define HDIM 512
#define SEGS 512
#define NPOS 8
#define NTAB 7     // position 0+1 merged
#define NW   1025
#define CCH  3

#define THREADS 512
#define TILE_X 128
#define TILE_Y 64
#define KITER  4                              // px advances 32 per k
#define TILES_PER_SLICE ((WDIM / TILE_X) * (HDIM / TILE_Y))  // 32

typedef float floatx4 __attribute__((ext_vector_type(4)));

struct Params {
    float ax[NPOS];
    float ay[NPOS];
    float c0[NPOS];
};

union HalfPack {
    unsigned int u;
    _Float16 h[2];
};

__global__ __launch_bounds__(THREADS, 8)
void stripe_poly_kernel(const float* __restrict__ x,
                        const float* __restrict__ w,
                        float* __restrict__ out,
                        Params P)
{
    // 7 tables x 512 segments x 8 B = 28 KB
    __shared__ uint2 lut[NTAB][SEGS];

    const int slice = blockIdx.x / TILES_PER_SLICE;   // b*3 + c
    const int tile  = blockIdx.x % TILES_PER_SLICE;
    const int ch    = slice % CCH;
    const int bx    = (tile >> 3) * TILE_X;   // px tile origin (4 x-tiles)
    const int by    = (tile & 7) * TILE_Y;    // py tile origin (8 y-tiles)

    // Stage coefficient LUT (1/8 folded in): 3584 entries / 512 thr = 7 ea.
    for (int idx = threadIdx.x; idx < NTAB * SEGS; idx += THREADS) {
        const int m = idx >> 9;            // merged table id (uniform per iter)
        const int s = idx & (SEGS - 1);
        float w0, w1, w2;
        if (m == 0) {
            const float* wa = w + (size_t)(0 * CCH + ch) * NW + 2 * s;
            const float* wb = w + (size_t)(1 * CCH + ch) * NW + 2 * s;
            w0 = wa[0] + wb[0]; w1 = wa[1] + wb[1]; w2 = wa[2] + wb[2];
        } else {
            const float* wp = w + (size_t)((m + 1) * CCH + ch) * NW + 2 * s;
            w0 = wp[0]; w1 = wp[1]; w2 = wp[2];
        }
        const float c0 = 0.125f * w1;
        const float c1 = 0.0625f * (w2 - w0);
        const float c2 = 0.125f * fmaf(0.5f, w0 + w2, -w1);
        HalfPack hp;
        hp.h[0] = (_Float16)c1;
        hp.h[1] = (_Float16)c2;
        lut[m][s] = make_uint2(__float_as_uint(c0), hp.u);
    }
    __syncthreads();

    // Lane -> patch mapping: wave covers 4 px rows x 64 contiguous py per k.
    const int tid  = threadIdx.x;
    const int wv   = tid >> 6;
    const int lane = tid & 63;
    const int px0  = bx + wv * 4 + (lane >> 4);          // k adds 32
    const int py   = by + (lane & 15) * 4;
    const float yf = (float)py;

    const size_t slice_off = (size_t)slice * (WDIM * HDIM);
    const size_t pbase = slice_off + (size_t)px0 * HDIM + py;

    // Hoist y-dependent part of each position map (py fixed across k).
    float gy[NTAB];
    #pragma unroll
    for (int i = 0; i < NTAB; ++i) {
        const int pi = (i == 0) ? 0 : (i + 1);
        gy[i] = fmaf(P.ay[pi], yf, P.c0[pi]);
    }

    // Software-pipelined k loop: prefetch x for k+1 before computing k.
    float4 xin = *(const float4*)(x + pbase);
    #pragma unroll
    for (int k = 0; k < KITER; ++k) {
        const size_t pk = pbase + (size_t)(k * 32) * HDIM;
        float4 xnext;
        if (k + 1 < KITER)
            xnext = *(const float4*)(x + pk + (size_t)32 * HDIM);

        const float xf = (float)(px0 + k * 32);
        const float xv[4] = {xin.x, xin.y, xin.z, xin.w};
        float acc[4] = {0.f, 0.f, 0.f, 0.f};

        #pragma unroll
        for (int i = 0; i < NTAB; ++i) {
            const int pi = (i == 0) ? 0 : (i + 1);  // source position index
            const float ay = P.ay[pi];
            const float g  = fmaf(P.ax[pi], xf, gy[i]);
            float gj[4];
            gj[0] = g;
            gj[1] = g + ay;
            gj[2] = gj[1] + ay;
            gj[3] = gj[2] + ay;
            #pragma unroll
            for (int j = 0; j < 4; ++j) {
                const float xs = fmaf(0.5f, xv[j], gj[j]);
                float sf = floorf(xs);
                sf = fminf(fmaxf(sf, 0.0f), (float)(SEGS - 1));  // v_med3
                const int s = (int)sf;
                const float t = fmaf(2.0f, xs - sf, -1.0f);
                const uint2 v = lut[i][s];                 // ds_read_b64
                HalfPack hp; hp.u = v.y;
                const float u = fmaf(t, (float)hp.h[1], (float)hp.h[0]); // fma_mix
                acc[j] = fmaf(t, u, acc[j] + __uint_as_float(v.x));
            }
        }

        floatx4 o;
        o.x = acc[0]; o.y = acc[1]; o.z = acc[2]; o.w = acc[3];
        __builtin_nontemporal_store(o, (floatx4*)(out + pk));
        xin = xnext;
    }
}

extern "C" void kernel_launch(void* const* d_in, const int* in_sizes, int n_in,
                              void* d_out, int out_size, void* d_ws, size_t ws_size,
                              hipStream_t stream)
{
    const float* x = (const float*)d_in[0];   // [16,3,512,512] f32
    const float* w = (const float*)d_in[1];   // [8,3,1025] f32
    float* out = (float*)d_out;

    // Host-side fold of make_positions() + position_encode + xs rescale.
    // r(x,y) = f32(cx)*x + f32(sgn*cy)*y ; extremes at grid corners (monotone).
    // xs = 0.5*xval + K*(r - rmin), K = 512*RATIO/dr  =>  Ax=K*a, Ay=K*b, C0=-K*rmin.
    Params P;
    const double ratio_f = (double)(float)(512.0 / 513.0);  // numpy casts RATIO to f32
    for (int i = 0; i < 4; ++i) {
        const double theta = (M_PI * 0.5) * ((double)i / 4.0);
        const float a   = (float)cos(theta);
        const float cyf = (float)sin(theta);
        for (int sg = 0; sg < 2; ++sg) {
            const float b = (sg == 0) ? cyf : -cyf;   // f32(sgn*cy)
            const float ax511 = a * 511.0f;
            const float by511 = b * 511.0f;
            float rmin, rmax;
            if (sg == 0) { rmin = 0.0f;  rmax = ax511 + by511; }
            else         { rmin = by511; rmax = ax511; }
            const float dr = rmax - rmin;
            const double K = 512.0 * ratio_f / (double)dr;
            const int pi = 2 * i + sg;
            P.ax[pi] = (float)(K * (double)a);
            P.ay[pi] = (float)(K * (double)b);
            P.c0[pi] = (float)(-K * (double)rmin);
        }
    }

    const int slices = in_sizes[0] / (WDIM * HDIM);  // B*C = 48
    const int blocks = slices * TILES_PER_SLICE;     // 1536
    stripe_poly_kernel<<<blocks, THREADS, 0, stream>>>(x, w, out, P);
}